// Round 5
// baseline (1067.553 us; speedup 1.0000x reference)
//
#include <hip/hip_runtime.h>
#include <hip/hip_cooperative_groups.h>

namespace cg = cooperative_groups;

// Affinity propagation, [X=256,Y=256,Z=32] fp32, 9 steps fused in ONE
// cooperative kernel with grid.sync() between steps. Grid size = occupancy
// query * 256 CUs (expected 8 blocks/CU -> 2048 blocks -> 1 float4-group per
// thread). Fallback: 9 separate dispatches if cooperative launch rejected.
//
// Per step (dir = step%3), per voxel v:
//   g_k  = guidance[dir*8+k][v+off_k]  (0 if off-grid in the stencil plane)
//   out[v] = r[v] + (sum_k g_k*(r[v+off_k]-r[v])) / (sum_k |g_k|)
// k -> (d1,d2): (1,1),(1,0),(1,-1),(0,1),(0,-1),(-1,1),(-1,0),(-1,-1)
//   dir0: (d1,d2)->(x,y)  dir1: (x,z)  dir2: (y,z)
//
// All loads unconditional at clamped in-allocation addresses; guidance is
// zero-masked for off-grid neighbors (g=0 kills the whole term == zero-pad).

constexpr int X = 256, Y = 256, Z = 32;
constexpr int NV = X * Y * Z;        // 2097152
constexpr int YZ = Y * Z;            // 8192
constexpr int NG = NV / 4;           // float4 groups
constexpr int GEND = 24 * NV;

__device__ __forceinline__ int iclamp(int v, int lo, int hi) {
    return min(max(v, lo), hi);
}

template <int DIR>
__device__ __forceinline__ void do_group(int f0, const float* __restrict__ g,
                                         const float* __restrict__ src,
                                         float* __restrict__ dst) {
    constexpr int d1[8] = {1, 1, 1, 0, 0, -1, -1, -1};
    constexpr int d2[8] = {1, 0, -1, 1, -1, 1, 0, -1};
    const int z = f0 & 31, y = (f0 >> 5) & 255, x = f0 >> 13;
    const int gb0 = DIR * 8 * NV;

    float asx = 0, asy = 0, asz = 0, asw = 0;
    float dx = 0, dy = 0, dz = 0, dw = 0;
    float4 rc;

    if (DIR == 0) {
        rc = *(const float4*)(src + f0);
#pragma unroll
        for (int k = 0; k < 8; ++k) {
            const int a = x + d1[k], b = y + d2[k];
            const bool valid = ((unsigned)a < 256u) & ((unsigned)b < 256u);
            const int ofs = f0 + d1[k] * YZ + d2[k] * Z;
            const float4 rv = *(const float4*)(src + iclamp(ofs, 0, NV - 4));
            float4 gv = *(const float4*)(g + iclamp(gb0 + k * NV + ofs, 0, GEND - 4));
            if (!valid) { gv.x = 0.f; gv.y = 0.f; gv.z = 0.f; gv.w = 0.f; }
            asx += fabsf(gv.x); asy += fabsf(gv.y);
            asz += fabsf(gv.z); asw += fabsf(gv.w);
            dx = fmaf(gv.x, rv.x - rc.x, dx); dy = fmaf(gv.y, rv.y - rc.y, dy);
            dz = fmaf(gv.z, rv.z - rc.z, dz); dw = fmaf(gv.w, rv.w - rc.w, dw);
        }
    } else {
        const int s1 = (DIR == 1) ? YZ : Z;   // d1 stride: x or y
        const int c1 = (DIR == 1) ? x : y;
        float4 rv[3]; float rl[3], rr[3];
#pragma unroll
        for (int j = 0; j < 3; ++j) {
            const int ro = f0 + (1 - j) * s1;
            rv[j] = *(const float4*)(src + iclamp(ro, 0, NV - 4));
            rl[j] = src[iclamp(ro - 1, 0, NV - 1)];
            rr[j] = src[iclamp(ro + 4, 0, NV - 1)];
        }
        rc = rv[1];
        const bool zlo = (z > 0), zhi = (z < Z - 4);
#pragma unroll
        for (int k = 0; k < 8; ++k) {
            const int j = 1 - d1[k];
            const bool vrow = (unsigned)(c1 + d1[k]) < 256u;
            const int gb = gb0 + k * NV + f0 + d1[k] * s1;
            float4 gv = *(const float4*)(g + iclamp(gb, 0, GEND - 4));
            if (!vrow) { gv.x = 0.f; gv.y = 0.f; gv.z = 0.f; gv.w = 0.f; }
            float4 gk, rk;
            if (d2[k] == 1) {
                float ge = g[iclamp(gb + 4, 0, GEND - 1)];
                ge = (vrow && zhi) ? ge : 0.f;
                gk = make_float4(gv.y, gv.z, gv.w, ge);
                rk = make_float4(rv[j].y, rv[j].z, rv[j].w, rr[j]);
            } else if (d2[k] == -1) {
                float ge = g[iclamp(gb - 1, 0, GEND - 1)];
                ge = (vrow && zlo) ? ge : 0.f;
                gk = make_float4(ge, gv.x, gv.y, gv.z);
                rk = make_float4(rl[j], rv[j].x, rv[j].y, rv[j].z);
            } else {
                gk = gv; rk = rv[j];
            }
            asx += fabsf(gk.x); asy += fabsf(gk.y);
            asz += fabsf(gk.z); asw += fabsf(gk.w);
            dx = fmaf(gk.x, rk.x - rc.x, dx); dy = fmaf(gk.y, rk.y - rc.y, dy);
            dz = fmaf(gk.z, rk.z - rc.z, dz); dw = fmaf(gk.w, rk.w - rc.w, dw);
        }
    }

    float4 o;
    o.x = rc.x + dx * __builtin_amdgcn_rcpf(asx);
    o.y = rc.y + dy * __builtin_amdgcn_rcpf(asy);
    o.z = rc.z + dz * __builtin_amdgcn_rcpf(asz);
    o.w = rc.w + dw * __builtin_amdgcn_rcpf(asw);
    *(float4*)(dst + f0) = o;
}

// ---- fused cooperative kernel, grid-stride over float4 groups ----
__global__ __launch_bounds__(256, 1) void prop_all(const float* __restrict__ g,
                                                   const float* __restrict__ blur,
                                                   float* __restrict__ bufA,
                                                   float* __restrict__ bufB,
                                                   float* __restrict__ out) {
    cg::grid_group grid = cg::this_grid();
    const int u = blockIdx.x * 256 + threadIdx.x;
    const int T = gridDim.x * 256;

    for (int step = 0; step < 9; ++step) {
        const float* src = (step == 0) ? blur : ((step & 1) ? bufA : bufB);
        float* dst = (step == 8) ? out : ((step & 1) ? bufB : bufA);
        const int dir = step % 3;

        if (dir == 0) {
            for (int idx = u; idx < NG; idx += T) do_group<0>(idx << 2, g, src, dst);
        } else if (dir == 1) {
            for (int idx = u; idx < NG; idx += T) do_group<1>(idx << 2, g, src, dst);
        } else {
            for (int idx = u; idx < NG; idx += T) do_group<2>(idx << 2, g, src, dst);
        }
        if (step < 8) grid.sync();
    }
}

// ---- fallback: one dispatch per step (known-good path, ~375 us) ----
template <int DIR>
__global__ __launch_bounds__(256) void prop_step(const float* __restrict__ g,
                                                 const float* __restrict__ rin,
                                                 float* __restrict__ rout) {
    const int t = blockIdx.x * 256 + threadIdx.x;
    do_group<DIR>(t << 2, g, rin, rout);
}

extern "C" void kernel_launch(void* const* d_in, const int* in_sizes, int n_in,
                              void* d_out, int out_size, void* d_ws, size_t ws_size,
                              hipStream_t stream) {
    const float* g    = (const float*)d_in[0];
    const float* blur = (const float*)d_in[1];
    float* out  = (float*)d_out;
    float* bufA = (float*)d_ws;
    float* bufB = bufA + NV;

    // Max co-resident cooperative grid for this kernel (host-side query, capture-safe).
    int nb = 0;
    hipError_t qe = hipOccupancyMaxActiveBlocksPerMultiprocessor(&nb, prop_all, 256, 0);
    if (qe != hipSuccess || nb < 1) nb = 1;
    if (nb > 8) nb = 8;                      // 8 blocks/CU = 32 waves/CU = HW cap
    const int nblocks = 256 * nb;

    void* args[] = {(void*)&g, (void*)&blur, (void*)&bufA, (void*)&bufB, (void*)&out};
    hipError_t err = hipLaunchCooperativeKernel((void*)prop_all, dim3(nblocks),
                                                dim3(256), args, 0, stream);
    if (err != hipSuccess) {
        (void)hipGetLastError();  // clear sticky error, fall back to 9 dispatches
        const dim3 grid(NG / 256), block(256);
        const float* src = blur;
        for (int step = 0; step < 9; ++step) {
            float* dst = (step == 8) ? out : ((step & 1) ? bufB : bufA);
            switch (step % 3) {
                case 0: prop_step<0><<<grid, block, 0, stream>>>(g, src, dst); break;
                case 1: prop_step<1><<<grid, block, 0, stream>>>(g, src, dst); break;
                case 2: prop_step<2><<<grid, block, 0, stream>>>(g, src, dst); break;
            }
            src = dst;
        }
    }
}

// Round 6
// 390.721 us; speedup vs baseline: 2.7323x; 2.7323x over previous
//
#include <hip/hip_runtime.h>
#include <hip/hip_fp16.h>

// Affinity propagation, [X=256,Y=256,Z=32] fp32, 3 iterations x 3 dirs.
//
// R6: weights are iteration-invariant -> precompute ONCE per call:
//   w_k[v] = g[dir*8+k][v+off_k] / sum_k |g[dir*8+k][v+off_k]|   (0 if OOB)
// packed as 8 x fp16 per voxel (16 B AoS record, one dwordx4 per voxel).
// Then 9 lightweight steps: out[v] = r[v] + sum_k w_k[v]*(r[v+off_k]-r[v])
// with zero masking/division in the hot kernels (OOB handled by w=0;
// r loads use clamped in-allocation addresses whose values are killed by w=0).
//
// k -> (d1,d2): (1,1),(1,0),(1,-1),(0,1),(0,-1),(-1,1),(-1,0),(-1,-1)
//   dir0: (d1,d2)->(x,y)   dir1: (x,z)   dir2: (y,z)
//
// Cooperative fusion abandoned: measured grid.sync ~ 180 us at 2048 blocks.

constexpr int X = 256, Y = 256, Z = 32;
constexpr int NV = X * Y * Z;        // 2097152
constexpr int YZ = Y * Z;            // 8192
constexpr int NG = NV / 4;           // float4 groups
constexpr int GEND = 24 * NV;

__device__ __forceinline__ int iclamp(int v, int lo, int hi) {
    return min(max(v, lo), hi);
}

struct alignas(16) H8 { __half2 h[4]; };   // 8 fp16 weights for one voxel

// ---------------- weight precompute (once per call) ----------------
template <int DIR>
__device__ __forceinline__ void wgroup(int f0, const float* __restrict__ g,
                                       H8* __restrict__ wd) {
    constexpr int d1[8] = {1, 1, 1, 0, 0, -1, -1, -1};
    constexpr int d2[8] = {1, 0, -1, 1, -1, 1, 0, -1};
    const int z = f0 & 31, y = (f0 >> 5) & 255, x = f0 >> 13;
    const int gb0 = DIR * 8 * NV;

    float G[8][4];

    if (DIR == 0) {
#pragma unroll
        for (int k = 0; k < 8; ++k) {
            const int a = x + d1[k], b = y + d2[k];
            const bool valid = ((unsigned)a < 256u) & ((unsigned)b < 256u);
            const int ofs = f0 + d1[k] * YZ + d2[k] * Z;
            float4 gv = *(const float4*)(g + iclamp(gb0 + k * NV + ofs, 0, GEND - 4));
            if (!valid) { gv.x = 0.f; gv.y = 0.f; gv.z = 0.f; gv.w = 0.f; }
            G[k][0] = gv.x; G[k][1] = gv.y; G[k][2] = gv.z; G[k][3] = gv.w;
        }
    } else {
        const int s1 = (DIR == 1) ? YZ : Z;
        const int c1 = (DIR == 1) ? x : y;
        const bool zlo = (z > 0), zhi = (z < Z - 4);
#pragma unroll
        for (int k = 0; k < 8; ++k) {
            const bool vrow = (unsigned)(c1 + d1[k]) < 256u;
            const int gb = gb0 + k * NV + f0 + d1[k] * s1;
            float4 gv = *(const float4*)(g + iclamp(gb, 0, GEND - 4));
            if (!vrow) { gv.x = 0.f; gv.y = 0.f; gv.z = 0.f; gv.w = 0.f; }
            if (d2[k] == 1) {
                float ge = g[iclamp(gb + 4, 0, GEND - 1)];
                ge = (vrow && zhi) ? ge : 0.f;
                G[k][0] = gv.y; G[k][1] = gv.z; G[k][2] = gv.w; G[k][3] = ge;
            } else if (d2[k] == -1) {
                float ge = g[iclamp(gb - 1, 0, GEND - 1)];
                ge = (vrow && zlo) ? ge : 0.f;
                G[k][0] = ge; G[k][1] = gv.x; G[k][2] = gv.y; G[k][3] = gv.z;
            } else {
                G[k][0] = gv.x; G[k][1] = gv.y; G[k][2] = gv.z; G[k][3] = gv.w;
            }
        }
    }

#pragma unroll
    for (int i = 0; i < 4; ++i) {
        float asum = 0.f;
#pragma unroll
        for (int k = 0; k < 8; ++k) asum += fabsf(G[k][i]);
        const float winv = __builtin_amdgcn_rcpf(asum);
        H8 rec;
#pragma unroll
        for (int p = 0; p < 4; ++p)
            rec.h[p] = __floats2half2_rn(G[2 * p][i] * winv, G[2 * p + 1][i] * winv);
        wd[f0 + i] = rec;
    }
}

__global__ __launch_bounds__(256) void make_w(const float* __restrict__ g,
                                              H8* __restrict__ wd) {
    const int b = blockIdx.x;
    const int dir = b >> 11;                 // 2048 blocks per dir
    const int f0 = ((b & 2047) * 256 + threadIdx.x) << 2;
    if (dir == 0)      wgroup<0>(f0, g, wd);
    else if (dir == 1) wgroup<1>(f0, g, wd + NV);
    else               wgroup<2>(f0, g, wd + 2 * NV);
}

// ---------------- hot step kernel: pure FMA, no masks ----------------
template <int DIR>
__global__ __launch_bounds__(256) void step_w(const H8* __restrict__ w,
                                              const float* __restrict__ rin,
                                              float* __restrict__ rout) {
    constexpr int d1[8] = {1, 1, 1, 0, 0, -1, -1, -1};
    constexpr int d2[8] = {1, 0, -1, 1, -1, 1, 0, -1};
    const int t  = blockIdx.x * 256 + threadIdx.x;
    const int f0 = t << 2;

    // 8 fp16 weights per voxel, 4 voxels
    H8 wv[4];
#pragma unroll
    for (int i = 0; i < 4; ++i) wv[i] = w[f0 + i];
    float W[4][8];
#pragma unroll
    for (int i = 0; i < 4; ++i)
#pragma unroll
        for (int p = 0; p < 4; ++p) {
            const float2 f = __half22float2(wv[i].h[p]);
            W[i][2 * p] = f.x; W[i][2 * p + 1] = f.y;
        }

    float4 rc;
    float D[8][4];                           // r[v+off_k] - r[v]

    if (DIR == 0) {
        rc = *(const float4*)(rin + f0);
#pragma unroll
        for (int k = 0; k < 8; ++k) {
            const int ofs = iclamp(f0 + d1[k] * YZ + d2[k] * Z, 0, NV - 4);
            const float4 rv = *(const float4*)(rin + ofs);
            D[k][0] = rv.x - rc.x; D[k][1] = rv.y - rc.y;
            D[k][2] = rv.z - rc.z; D[k][3] = rv.w - rc.w;
        }
    } else {
        const int s1 = (DIR == 1) ? YZ : Z;
        float4 rv[3]; float rl[3], rr[3];
#pragma unroll
        for (int j = 0; j < 3; ++j) {
            const int ro = f0 + (1 - j) * s1;
            rv[j] = *(const float4*)(rin + iclamp(ro, 0, NV - 4));
            rl[j] = rin[iclamp(ro - 1, 0, NV - 1)];
            rr[j] = rin[iclamp(ro + 4, 0, NV - 1)];
        }
        rc = rv[1];
#pragma unroll
        for (int k = 0; k < 8; ++k) {
            const int j = 1 - d1[k];
            float4 rk;
            if (d2[k] == 1)       rk = make_float4(rv[j].y, rv[j].z, rv[j].w, rr[j]);
            else if (d2[k] == -1) rk = make_float4(rl[j], rv[j].x, rv[j].y, rv[j].z);
            else                  rk = rv[j];
            D[k][0] = rk.x - rc.x; D[k][1] = rk.y - rc.y;
            D[k][2] = rk.z - rc.z; D[k][3] = rk.w - rc.w;
        }
    }

    float o[4] = {rc.x, rc.y, rc.z, rc.w};
#pragma unroll
    for (int i = 0; i < 4; ++i)
#pragma unroll
        for (int k = 0; k < 8; ++k) o[i] = fmaf(W[i][k], D[k][i], o[i]);
    *(float4*)(rout + f0) = make_float4(o[0], o[1], o[2], o[3]);
}

// ---------------- fallback (R1-proven): direct-from-guidance step ----------------
template <int DIR>
__global__ __launch_bounds__(256) void prop_step(const float* __restrict__ g,
                                                 const float* __restrict__ rin,
                                                 float* __restrict__ rout) {
    constexpr int d1[8] = {1, 1, 1, 0, 0, -1, -1, -1};
    constexpr int d2[8] = {1, 0, -1, 1, -1, 1, 0, -1};
    const int t = blockIdx.x * 256 + threadIdx.x;
    const int f0 = t << 2;
    const int z = f0 & 31, y = (f0 >> 5) & 255, x = f0 >> 13;
    const int gb0 = DIR * 8 * NV;

    float as[4] = {0, 0, 0, 0}, ac[4] = {0, 0, 0, 0};
    float4 rc;

    if (DIR == 0) {
        rc = *(const float4*)(rin + f0);
#pragma unroll
        for (int k = 0; k < 8; ++k) {
            const int a = x + d1[k], b = y + d2[k];
            const bool valid = ((unsigned)a < 256u) & ((unsigned)b < 256u);
            const int ofs = f0 + d1[k] * YZ + d2[k] * Z;
            const float4 rv = *(const float4*)(rin + iclamp(ofs, 0, NV - 4));
            float4 gv = *(const float4*)(g + iclamp(gb0 + k * NV + ofs, 0, GEND - 4));
            if (!valid) { gv.x = 0.f; gv.y = 0.f; gv.z = 0.f; gv.w = 0.f; }
            as[0] += fabsf(gv.x); as[1] += fabsf(gv.y);
            as[2] += fabsf(gv.z); as[3] += fabsf(gv.w);
            ac[0] = fmaf(gv.x, rv.x - rc.x, ac[0]); ac[1] = fmaf(gv.y, rv.y - rc.y, ac[1]);
            ac[2] = fmaf(gv.z, rv.z - rc.z, ac[2]); ac[3] = fmaf(gv.w, rv.w - rc.w, ac[3]);
        }
    } else {
        const int s1 = (DIR == 1) ? YZ : Z;
        const int c1 = (DIR == 1) ? x : y;
        float4 rv[3]; float rl[3], rr[3];
#pragma unroll
        for (int j = 0; j < 3; ++j) {
            const int ro = f0 + (1 - j) * s1;
            rv[j] = *(const float4*)(rin + iclamp(ro, 0, NV - 4));
            rl[j] = rin[iclamp(ro - 1, 0, NV - 1)];
            rr[j] = rin[iclamp(ro + 4, 0, NV - 1)];
        }
        rc = rv[1];
        const bool zlo = (z > 0), zhi = (z < Z - 4);
#pragma unroll
        for (int k = 0; k < 8; ++k) {
            const int j = 1 - d1[k];
            const bool vrow = (unsigned)(c1 + d1[k]) < 256u;
            const int gb = gb0 + k * NV + f0 + d1[k] * s1;
            float4 gv = *(const float4*)(g + iclamp(gb, 0, GEND - 4));
            if (!vrow) { gv.x = 0.f; gv.y = 0.f; gv.z = 0.f; gv.w = 0.f; }
            float4 gk, rk;
            if (d2[k] == 1) {
                float ge = g[iclamp(gb + 4, 0, GEND - 1)];
                ge = (vrow && zhi) ? ge : 0.f;
                gk = make_float4(gv.y, gv.z, gv.w, ge);
                rk = make_float4(rv[j].y, rv[j].z, rv[j].w, rr[j]);
            } else if (d2[k] == -1) {
                float ge = g[iclamp(gb - 1, 0, GEND - 1)];
                ge = (vrow && zlo) ? ge : 0.f;
                gk = make_float4(ge, gv.x, gv.y, gv.z);
                rk = make_float4(rl[j], rv[j].x, rv[j].y, rv[j].z);
            } else {
                gk = gv; rk = rv[j];
            }
            as[0] += fabsf(gk.x); as[1] += fabsf(gk.y);
            as[2] += fabsf(gk.z); as[3] += fabsf(gk.w);
            ac[0] = fmaf(gk.x, rk.x - rc.x, ac[0]); ac[1] = fmaf(gk.y, rk.y - rc.y, ac[1]);
            ac[2] = fmaf(gk.z, rk.z - rc.z, ac[2]); ac[3] = fmaf(gk.w, rk.w - rc.w, ac[3]);
        }
    }

    float4 o;
    o.x = rc.x + ac[0] * __builtin_amdgcn_rcpf(as[0]);
    o.y = rc.y + ac[1] * __builtin_amdgcn_rcpf(as[1]);
    o.z = rc.z + ac[2] * __builtin_amdgcn_rcpf(as[2]);
    o.w = rc.w + ac[3] * __builtin_amdgcn_rcpf(as[3]);
    *(float4*)(rout + f0) = o;
}

extern "C" void kernel_launch(void* const* d_in, const int* in_sizes, int n_in,
                              void* d_out, int out_size, void* d_ws, size_t ws_size,
                              hipStream_t stream) {
    const float* g    = (const float*)d_in[0];
    const float* blur = (const float*)d_in[1];
    float* out = (float*)d_out;

    const size_t WBYTES = (size_t)3 * NV * sizeof(H8);       // 96 MiB
    const size_t NEED   = WBYTES + (size_t)NV * sizeof(float);
    const dim3 block(256), sgrid(NG / 256);

    if (ws_size >= NEED) {
        H8*    wd   = (H8*)d_ws;
        float* bufA = (float*)((char*)d_ws + WBYTES);

        make_w<<<dim3(3 * NG / 256), block, 0, stream>>>(g, wd);

        // ping-pong: step0 -> out, step1 -> bufA, ..., step8 -> out
        const float* src = blur;
        for (int step = 0; step < 9; ++step) {
            float* dst = (step & 1) ? bufA : out;
            const H8* w = wd + (size_t)(step % 3) * NV;
            switch (step % 3) {
                case 0: step_w<0><<<sgrid, block, 0, stream>>>(w, src, dst); break;
                case 1: step_w<1><<<sgrid, block, 0, stream>>>(w, src, dst); break;
                case 2: step_w<2><<<sgrid, block, 0, stream>>>(w, src, dst); break;
            }
            src = dst;
        }
    } else {
        // fallback: R1-proven direct path (needs only 8 MiB of ws)
        float* ws = (float*)d_ws;
        const float* src = blur;
        for (int step = 0; step < 9; ++step) {
            float* dst = (step & 1) ? ws : out;
            switch (step % 3) {
                case 0: prop_step<0><<<sgrid, block, 0, stream>>>(g, src, dst); break;
                case 1: prop_step<1><<<sgrid, block, 0, stream>>>(g, src, dst); break;
                case 2: prop_step<2><<<sgrid, block, 0, stream>>>(g, src, dst); break;
            }
            src = dst;
        }
    }
}

// Round 7
// 357.749 us; speedup vs baseline: 2.9841x; 1.0922x over previous
//
#include <hip/hip_runtime.h>
#include <hip/hip_fp16.h>

// Affinity propagation, [X=256,Y=256,Z=32] fp32, 3 iterations x 3 dirs.
//
// R7: dispatch-boundary cost (~30 us each) dominates, so fuse each iteration
// (dir0 x/y, dir1 x/z, dir2 y/z) into ONE kernel via LDS halo recomputation:
//   - weights precomputed once (fp16, normalized, OOB->0), stored TRANSPOSED
//     as [dir][z][x][y] 16B records so in-kernel loads are lane-coalesced
//   - block tile 8x16 (x,y), region 12x20 (halo 2), z=32 resident in LDS
//   - two LDS buffers ping-pong across the 3 steps; 512 blocks (2/CU)
//   - OOB correctness: cross-edge weights are 0, so garbage halo values are
//     always annihilated; LDS zero-init prevents NaN*0.
// Total dispatches: 10 -> 4 (make_w + 3x iter3).

constexpr int NV = 256 * 256 * 32;   // 2097152
constexpr int YZ = 256 * 32;         // 8192
constexpr int NG = NV / 4;
constexpr int GEND = 24 * NV;

constexpr int TXB = 8, TYB = 16;     // output tile per block
constexpr int RX = 12, RY = 20;      // input region (halo 2 each side)
constexpr int NCOL = RX * RY;        // 240 columns
constexpr int CSTR = 33;             // LDS column stride (odd => conflict-free)
constexpr int LOFF = 16;             // guard so z-1/z+1 reads stay in-array
constexpr int LSZ = NCOL * CSTR + 2 * LOFF;

struct alignas(16) H8 { __half2 h[4]; };   // 8 fp16 weights per voxel

__device__ __forceinline__ int iclamp(int v, int lo, int hi) {
    return min(max(v, lo), hi);
}

// ---------------- weight precompute (transposed store) ----------------
template <int DIR>
__device__ __forceinline__ void wgroup_t(int f0, const float* __restrict__ g,
                                         H8* __restrict__ wt) {
    constexpr int d1[8] = {1, 1, 1, 0, 0, -1, -1, -1};
    constexpr int d2[8] = {1, 0, -1, 1, -1, 1, 0, -1};
    const int z = f0 & 31, y = (f0 >> 5) & 255, x = f0 >> 13;
    const int gb0 = DIR * 8 * NV;

    float G[8][4];

    if (DIR == 0) {
#pragma unroll
        for (int k = 0; k < 8; ++k) {
            const int a = x + d1[k], b = y + d2[k];
            const bool valid = ((unsigned)a < 256u) & ((unsigned)b < 256u);
            const int ofs = f0 + d1[k] * YZ + d2[k] * 32;
            float4 gv = *(const float4*)(g + iclamp(gb0 + k * NV + ofs, 0, GEND - 4));
            if (!valid) { gv.x = 0.f; gv.y = 0.f; gv.z = 0.f; gv.w = 0.f; }
            G[k][0] = gv.x; G[k][1] = gv.y; G[k][2] = gv.z; G[k][3] = gv.w;
        }
    } else {
        const int s1 = (DIR == 1) ? YZ : 32;
        const int c1 = (DIR == 1) ? x : y;
        const bool zlo = (z > 0), zhi = (z < 28);
#pragma unroll
        for (int k = 0; k < 8; ++k) {
            const bool vrow = (unsigned)(c1 + d1[k]) < 256u;
            const int gb = gb0 + k * NV + f0 + d1[k] * s1;
            float4 gv = *(const float4*)(g + iclamp(gb, 0, GEND - 4));
            if (!vrow) { gv.x = 0.f; gv.y = 0.f; gv.z = 0.f; gv.w = 0.f; }
            if (d2[k] == 1) {
                float ge = g[iclamp(gb + 4, 0, GEND - 1)];
                ge = (vrow && zhi) ? ge : 0.f;
                G[k][0] = gv.y; G[k][1] = gv.z; G[k][2] = gv.w; G[k][3] = ge;
            } else if (d2[k] == -1) {
                float ge = g[iclamp(gb - 1, 0, GEND - 1)];
                ge = (vrow && zlo) ? ge : 0.f;
                G[k][0] = ge; G[k][1] = gv.x; G[k][2] = gv.y; G[k][3] = gv.z;
            } else {
                G[k][0] = gv.x; G[k][1] = gv.y; G[k][2] = gv.z; G[k][3] = gv.w;
            }
        }
    }

#pragma unroll
    for (int i = 0; i < 4; ++i) {
        float asum = 0.f;
#pragma unroll
        for (int k = 0; k < 8; ++k) asum += fabsf(G[k][i]);
        const float winv = __builtin_amdgcn_rcpf(asum);
        H8 rec;
#pragma unroll
        for (int p = 0; p < 4; ++p)
            rec.h[p] = __floats2half2_rn(G[2 * p][i] * winv, G[2 * p + 1][i] * winv);
        const int zz = (f0 + i) & 31;
        wt[((DIR * 32 + zz) << 16) + (x << 8) + y] = rec;
    }
}

__global__ __launch_bounds__(256) void make_w(const float* __restrict__ g,
                                              H8* __restrict__ wt) {
    const int b = blockIdx.x;
    const int dir = b >> 11;                 // 2048 blocks per dir
    const int f0 = ((b & 2047) * 256 + threadIdx.x) << 2;
    if (dir == 0)      wgroup_t<0>(f0, g, wt);
    else if (dir == 1) wgroup_t<1>(f0, g, wt);
    else               wgroup_t<2>(f0, g, wt);
}

// ---------------- fused 3-step (one iteration) kernel ----------------
template <int DIR, bool STORE>
__device__ __forceinline__ void fstep(const H8* __restrict__ wt,
                                      const float* __restrict__ src,
                                      float* __restrict__ dst,      // LDS (if !STORE)
                                      float* __restrict__ gq,       // global col (if STORE)
                                      int cb, int gxc, int gyc, bool in) {
    if (!in) return;
    const int wb = ((DIR * 32) << 16) + (gxc << 8) + gyc;
#pragma unroll 16
    for (int z = 0; z < 32; ++z) {
        const H8 wr = wt[wb + (z << 16)];
        float w[8]; float2 f;
        f = __half22float2(wr.h[0]); w[0] = f.x; w[1] = f.y;
        f = __half22float2(wr.h[1]); w[2] = f.x; w[3] = f.y;
        f = __half22float2(wr.h[2]); w[4] = f.x; w[5] = f.y;
        f = __half22float2(wr.h[3]); w[6] = f.x; w[7] = f.y;
        const float rc = src[cb + z];
        float a = rc;
        if (DIR == 0) {              // (x+-1, y+-1), same z
            a = fmaf(w[0], src[cb + z + (RY + 1) * CSTR] - rc, a);
            a = fmaf(w[1], src[cb + z +  RY      * CSTR] - rc, a);
            a = fmaf(w[2], src[cb + z + (RY - 1) * CSTR] - rc, a);
            a = fmaf(w[3], src[cb + z +            CSTR] - rc, a);
            a = fmaf(w[4], src[cb + z -            CSTR] - rc, a);
            a = fmaf(w[5], src[cb + z - (RY - 1) * CSTR] - rc, a);
            a = fmaf(w[6], src[cb + z -  RY      * CSTR] - rc, a);
            a = fmaf(w[7], src[cb + z - (RY + 1) * CSTR] - rc, a);
        } else if (DIR == 1) {       // (x+-1, z+-1)
            a = fmaf(w[0], src[cb + z + 1 + RY * CSTR] - rc, a);
            a = fmaf(w[1], src[cb + z     + RY * CSTR] - rc, a);
            a = fmaf(w[2], src[cb + z - 1 + RY * CSTR] - rc, a);
            a = fmaf(w[3], src[cb + z + 1] - rc, a);
            a = fmaf(w[4], src[cb + z - 1] - rc, a);
            a = fmaf(w[5], src[cb + z + 1 - RY * CSTR] - rc, a);
            a = fmaf(w[6], src[cb + z     - RY * CSTR] - rc, a);
            a = fmaf(w[7], src[cb + z - 1 - RY * CSTR] - rc, a);
        } else {                     // (y+-1, z+-1)
            a = fmaf(w[0], src[cb + z + 1 + CSTR] - rc, a);
            a = fmaf(w[1], src[cb + z     + CSTR] - rc, a);
            a = fmaf(w[2], src[cb + z - 1 + CSTR] - rc, a);
            a = fmaf(w[3], src[cb + z + 1] - rc, a);
            a = fmaf(w[4], src[cb + z - 1] - rc, a);
            a = fmaf(w[5], src[cb + z + 1 - CSTR] - rc, a);
            a = fmaf(w[6], src[cb + z     - CSTR] - rc, a);
            a = fmaf(w[7], src[cb + z - 1 - CSTR] - rc, a);
        }
        if (STORE) gq[z] = a;
        else       dst[cb + z] = a;
    }
}

__global__ __launch_bounds__(256) void iter3(const H8* __restrict__ wt,
                                             const float* __restrict__ rin,
                                             float* __restrict__ rout) {
    __shared__ float A[LSZ];
    __shared__ float B[LSZ];
    const int t  = threadIdx.x;
    const int bx = blockIdx.x & 31, by = blockIdx.x >> 5;  // 32 x 16 blocks
    const bool act = t < NCOL;
    const int rx = t / RY, ry = t - rx * RY;
    const int gx = bx * TXB - 2 + rx, gy = by * TYB - 2 + ry;
    const int gxc = iclamp(gx, 0, 255), gyc = iclamp(gy, 0, 255);
    const int cb = t * CSTR + LOFF;

    for (int i = t; i < LSZ; i += 256) { A[i] = 0.f; B[i] = 0.f; }
    __syncthreads();
    if (act) {
        const float* p = rin + ((gxc << 8) + gyc) * 32;
#pragma unroll
        for (int j = 0; j < 8; ++j) {
            const float4 v = *(const float4*)(p + 4 * j);
            A[cb + 4 * j]     = v.x; A[cb + 4 * j + 1] = v.y;
            A[cb + 4 * j + 2] = v.z; A[cb + 4 * j + 3] = v.w;
        }
    }
    __syncthreads();

    const bool in0 = act && rx >= 1 && rx <= RX - 2 && ry >= 1 && ry <= RY - 2;
    const bool in1 = act && rx >= 2 && rx <= RX - 3 && ry >= 1 && ry <= RY - 2;
    const bool in2 = act && rx >= 2 && rx <= RX - 3 && ry >= 2 && ry <= RY - 3;

    fstep<0, false>(wt, A, B, nullptr, cb, gxc, gyc, in0);
    __syncthreads();
    fstep<1, false>(wt, B, A, nullptr, cb, gxc, gyc, in1);
    __syncthreads();
    float* gq = rout + ((gx << 8) + gy) * 32;   // in2 => gx,gy in-volume
    fstep<2, true>(wt, A, nullptr, gq, cb, gxc, gyc, in2);
}

// ---------------- fallback (R1-proven): direct-from-guidance steps ----------------
template <int DIR>
__global__ __launch_bounds__(256) void prop_step(const float* __restrict__ g,
                                                 const float* __restrict__ rin,
                                                 float* __restrict__ rout) {
    constexpr int d1[8] = {1, 1, 1, 0, 0, -1, -1, -1};
    constexpr int d2[8] = {1, 0, -1, 1, -1, 1, 0, -1};
    const int t = blockIdx.x * 256 + threadIdx.x;
    const int f0 = t << 2;
    const int z = f0 & 31, y = (f0 >> 5) & 255, x = f0 >> 13;
    const int gb0 = DIR * 8 * NV;

    float as[4] = {0, 0, 0, 0}, ac[4] = {0, 0, 0, 0};
    float4 rc;

    if (DIR == 0) {
        rc = *(const float4*)(rin + f0);
#pragma unroll
        for (int k = 0; k < 8; ++k) {
            const int a = x + d1[k], b = y + d2[k];
            const bool valid = ((unsigned)a < 256u) & ((unsigned)b < 256u);
            const int ofs = f0 + d1[k] * YZ + d2[k] * 32;
            const float4 rv = *(const float4*)(rin + iclamp(ofs, 0, NV - 4));
            float4 gv = *(const float4*)(g + iclamp(gb0 + k * NV + ofs, 0, GEND - 4));
            if (!valid) { gv.x = 0.f; gv.y = 0.f; gv.z = 0.f; gv.w = 0.f; }
            as[0] += fabsf(gv.x); as[1] += fabsf(gv.y);
            as[2] += fabsf(gv.z); as[3] += fabsf(gv.w);
            ac[0] = fmaf(gv.x, rv.x - rc.x, ac[0]); ac[1] = fmaf(gv.y, rv.y - rc.y, ac[1]);
            ac[2] = fmaf(gv.z, rv.z - rc.z, ac[2]); ac[3] = fmaf(gv.w, rv.w - rc.w, ac[3]);
        }
    } else {
        const int s1 = (DIR == 1) ? YZ : 32;
        const int c1 = (DIR == 1) ? x : y;
        float4 rv[3]; float rl[3], rr[3];
#pragma unroll
        for (int j = 0; j < 3; ++j) {
            const int ro = f0 + (1 - j) * s1;
            rv[j] = *(const float4*)(rin + iclamp(ro, 0, NV - 4));
            rl[j] = rin[iclamp(ro - 1, 0, NV - 1)];
            rr[j] = rin[iclamp(ro + 4, 0, NV - 1)];
        }
        rc = rv[1];
        const bool zlo = (z > 0), zhi = (z < 28);
#pragma unroll
        for (int k = 0; k < 8; ++k) {
            const int j = 1 - d1[k];
            const bool vrow = (unsigned)(c1 + d1[k]) < 256u;
            const int gb = gb0 + k * NV + f0 + d1[k] * s1;
            float4 gv = *(const float4*)(g + iclamp(gb, 0, GEND - 4));
            if (!vrow) { gv.x = 0.f; gv.y = 0.f; gv.z = 0.f; gv.w = 0.f; }
            float4 gk, rk;
            if (d2[k] == 1) {
                float ge = g[iclamp(gb + 4, 0, GEND - 1)];
                ge = (vrow && zhi) ? ge : 0.f;
                gk = make_float4(gv.y, gv.z, gv.w, ge);
                rk = make_float4(rv[j].y, rv[j].z, rv[j].w, rr[j]);
            } else if (d2[k] == -1) {
                float ge = g[iclamp(gb - 1, 0, GEND - 1)];
                ge = (vrow && zlo) ? ge : 0.f;
                gk = make_float4(ge, gv.x, gv.y, gv.z);
                rk = make_float4(rl[j], rv[j].x, rv[j].y, rv[j].z);
            } else {
                gk = gv; rk = rv[j];
            }
            as[0] += fabsf(gk.x); as[1] += fabsf(gk.y);
            as[2] += fabsf(gk.z); as[3] += fabsf(gk.w);
            ac[0] = fmaf(gk.x, rk.x - rc.x, ac[0]); ac[1] = fmaf(gk.y, rk.y - rc.y, ac[1]);
            ac[2] = fmaf(gk.z, rk.z - rc.z, ac[2]); ac[3] = fmaf(gk.w, rk.w - rc.w, ac[3]);
        }
    }

    float4 o;
    o.x = rc.x + ac[0] * __builtin_amdgcn_rcpf(as[0]);
    o.y = rc.y + ac[1] * __builtin_amdgcn_rcpf(as[1]);
    o.z = rc.z + ac[2] * __builtin_amdgcn_rcpf(as[2]);
    o.w = rc.w + ac[3] * __builtin_amdgcn_rcpf(as[3]);
    *(float4*)(rout + f0) = o;
}

extern "C" void kernel_launch(void* const* d_in, const int* in_sizes, int n_in,
                              void* d_out, int out_size, void* d_ws, size_t ws_size,
                              hipStream_t stream) {
    const float* g    = (const float*)d_in[0];
    const float* blur = (const float*)d_in[1];
    float* out = (float*)d_out;

    const size_t WBYTES = (size_t)3 * NV * sizeof(H8);            // 96 MiB
    const size_t NEED   = WBYTES + (size_t)2 * NV * sizeof(float);

    if (ws_size >= NEED) {
        H8*    wt   = (H8*)d_ws;
        float* bufA = (float*)((char*)d_ws + WBYTES);
        float* bufB = bufA + NV;

        make_w<<<dim3(3 * NG / 256), dim3(256), 0, stream>>>(g, wt);
        iter3<<<dim3(512), dim3(256), 0, stream>>>(wt, blur, bufA);
        iter3<<<dim3(512), dim3(256), 0, stream>>>(wt, bufA, bufB);
        iter3<<<dim3(512), dim3(256), 0, stream>>>(wt, bufB, out);
    } else {
        // fallback: R1-proven direct path (needs only 8 MiB of ws)
        float* ws = (float*)d_ws;
        const dim3 block(256), sgrid(NG / 256);
        const float* src = blur;
        for (int step = 0; step < 9; ++step) {
            float* dst = (step & 1) ? ws : out;
            switch (step % 3) {
                case 0: prop_step<0><<<sgrid, block, 0, stream>>>(g, src, dst); break;
                case 1: prop_step<1><<<sgrid, block, 0, stream>>>(g, src, dst); break;
                case 2: prop_step<2><<<sgrid, block, 0, stream>>>(g, src, dst); break;
            }
            src = dst;
        }
    }
}

// Round 8
// 357.265 us; speedup vs baseline: 2.9881x; 1.0014x over previous
//
#include <hip/hip_runtime.h>
#include <hip/hip_fp16.h>

// Affinity propagation, [X=256,Y=256,Z=32] fp32, 3 iterations x 3 dirs.
//
// R8 = R7 (fp16 weights precomputed once, transposed [dir][z][x][y]; each
// iteration's 3 steps fused in one kernel via LDS halo) + vectorized inner
// loops: z processed in chunks of 4, ds_read_b128 LDS access (CSTR=36 for
// 16B alignment), 4 weight records prefetched per chunk, float4 stores.
// OOB semantics ride on weights==0 across edges; LDS zero-init + per-column
// pad slot keeps z-edge reads benign (always multiplied by 0).

constexpr int NV = 256 * 256 * 32;   // 2097152
constexpr int YZ = 256 * 32;         // 8192
constexpr int NG = NV / 4;
constexpr int GEND = 24 * NV;

constexpr int TXB = 8, TYB = 16;     // output tile per block
constexpr int RX = 12, RY = 20;      // input region (halo 2 each side)
constexpr int NCOL = RX * RY;        // 240 columns
constexpr int CSTR = 36;             // column stride (16B-aligned columns)
constexpr int LOFF = 16;             // guard for z-1 read of column 0
constexpr int LSZ = NCOL * CSTR + 2 * LOFF;

struct alignas(16) H8 { __half2 h[4]; };   // 8 fp16 weights per voxel

__device__ __forceinline__ int iclamp(int v, int lo, int hi) {
    return min(max(v, lo), hi);
}

__device__ __forceinline__ void unpack8(const H8& r, float* w) {
    float2 f;
    f = __half22float2(r.h[0]); w[0] = f.x; w[1] = f.y;
    f = __half22float2(r.h[1]); w[2] = f.x; w[3] = f.y;
    f = __half22float2(r.h[2]); w[4] = f.x; w[5] = f.y;
    f = __half22float2(r.h[3]); w[6] = f.x; w[7] = f.y;
}

// ---------------- weight precompute (transposed store) ----------------
template <int DIR>
__device__ __forceinline__ void wgroup_t(int f0, const float* __restrict__ g,
                                         H8* __restrict__ wt) {
    constexpr int d1[8] = {1, 1, 1, 0, 0, -1, -1, -1};
    constexpr int d2[8] = {1, 0, -1, 1, -1, 1, 0, -1};
    const int z = f0 & 31, y = (f0 >> 5) & 255, x = f0 >> 13;
    const int gb0 = DIR * 8 * NV;

    float G[8][4];

    if (DIR == 0) {
#pragma unroll
        for (int k = 0; k < 8; ++k) {
            const int a = x + d1[k], b = y + d2[k];
            const bool valid = ((unsigned)a < 256u) & ((unsigned)b < 256u);
            const int ofs = f0 + d1[k] * YZ + d2[k] * 32;
            float4 gv = *(const float4*)(g + iclamp(gb0 + k * NV + ofs, 0, GEND - 4));
            if (!valid) { gv.x = 0.f; gv.y = 0.f; gv.z = 0.f; gv.w = 0.f; }
            G[k][0] = gv.x; G[k][1] = gv.y; G[k][2] = gv.z; G[k][3] = gv.w;
        }
    } else {
        const int s1 = (DIR == 1) ? YZ : 32;
        const int c1 = (DIR == 1) ? x : y;
        const bool zlo = (z > 0), zhi = (z < 28);
#pragma unroll
        for (int k = 0; k < 8; ++k) {
            const bool vrow = (unsigned)(c1 + d1[k]) < 256u;
            const int gb = gb0 + k * NV + f0 + d1[k] * s1;
            float4 gv = *(const float4*)(g + iclamp(gb, 0, GEND - 4));
            if (!vrow) { gv.x = 0.f; gv.y = 0.f; gv.z = 0.f; gv.w = 0.f; }
            if (d2[k] == 1) {
                float ge = g[iclamp(gb + 4, 0, GEND - 1)];
                ge = (vrow && zhi) ? ge : 0.f;
                G[k][0] = gv.y; G[k][1] = gv.z; G[k][2] = gv.w; G[k][3] = ge;
            } else if (d2[k] == -1) {
                float ge = g[iclamp(gb - 1, 0, GEND - 1)];
                ge = (vrow && zlo) ? ge : 0.f;
                G[k][0] = ge; G[k][1] = gv.x; G[k][2] = gv.y; G[k][3] = gv.z;
            } else {
                G[k][0] = gv.x; G[k][1] = gv.y; G[k][2] = gv.z; G[k][3] = gv.w;
            }
        }
    }

#pragma unroll
    for (int i = 0; i < 4; ++i) {
        float asum = 0.f;
#pragma unroll
        for (int k = 0; k < 8; ++k) asum += fabsf(G[k][i]);
        const float winv = __builtin_amdgcn_rcpf(asum);
        H8 rec;
#pragma unroll
        for (int p = 0; p < 4; ++p)
            rec.h[p] = __floats2half2_rn(G[2 * p][i] * winv, G[2 * p + 1][i] * winv);
        const int zz = (f0 + i) & 31;
        wt[((DIR * 32 + zz) << 16) + (x << 8) + y] = rec;
    }
}

__global__ __launch_bounds__(256) void make_w(const float* __restrict__ g,
                                              H8* __restrict__ wt) {
    const int b = blockIdx.x;
    const int dir = b >> 11;                 // 2048 blocks per dir
    const int f0 = ((b & 2047) * 256 + threadIdx.x) << 2;
    if (dir == 0)      wgroup_t<0>(f0, g, wt);
    else if (dir == 1) wgroup_t<1>(f0, g, wt);
    else               wgroup_t<2>(f0, g, wt);
}

// ---------------- fused 3-step (one iteration) kernel ----------------
template <int DIR, bool STORE>
__device__ __forceinline__ void fstep(const H8* __restrict__ wt,
                                      const float* __restrict__ src,  // LDS
                                      float* __restrict__ dst,        // LDS (!STORE)
                                      float* __restrict__ gq,         // global (STORE)
                                      int cb, int gxc, int gyc, bool in) {
    if (!in) return;
    const H8* wp = wt + ((DIR * 32) << 16) + (gxc << 8) + gyc;

#pragma unroll
    for (int zb = 0; zb < 32; zb += 4) {
        H8 wr[4];
#pragma unroll
        for (int i = 0; i < 4; ++i) wr[i] = wp[(zb + i) << 16];

        float out4[4];
        if (DIR == 0) {
            constexpr int ofs[8] = {RY + 1, RY, RY - 1, 1, -1, -(RY - 1), -RY, -(RY + 1)};
            const float4 vc = *(const float4*)(src + cb + zb);
            const float rc4[4] = {vc.x, vc.y, vc.z, vc.w};
            float nb[8][4];
#pragma unroll
            for (int k = 0; k < 8; ++k) {
                const float4 v = *(const float4*)(src + cb + zb + ofs[k] * CSTR);
                nb[k][0] = v.x; nb[k][1] = v.y; nb[k][2] = v.z; nb[k][3] = v.w;
            }
#pragma unroll
            for (int i = 0; i < 4; ++i) {
                float w[8]; unpack8(wr[i], w);
                float a = rc4[i];
#pragma unroll
                for (int k = 0; k < 8; ++k) a = fmaf(w[k], nb[k][i] - rc4[i], a);
                out4[i] = a;
            }
        } else {
            constexpr int S = (DIR == 1) ? RY : 1;   // d1 column step: x or y
            float v[3][4], lo[3], hi[3];
#pragma unroll
            for (int j = 0; j < 3; ++j) {            // d1 = +1, 0, -1
                const int cofs = cb + zb + (1 - j) * S * CSTR;
                const float4 t4 = *(const float4*)(src + cofs);
                v[j][0] = t4.x; v[j][1] = t4.y; v[j][2] = t4.z; v[j][3] = t4.w;
                lo[j] = src[cofs - 1];
                hi[j] = src[cofs + 4];
            }
#pragma unroll
            for (int i = 0; i < 4; ++i) {
                float w[8]; unpack8(wr[i], w);
                const float rc  = v[1][i];
                const float zp0 = (i < 3) ? v[0][i + 1] : hi[0];
                const float zm0 = (i > 0) ? v[0][i - 1] : lo[0];
                const float zp1 = (i < 3) ? v[1][i + 1] : hi[1];
                const float zm1 = (i > 0) ? v[1][i - 1] : lo[1];
                const float zp2 = (i < 3) ? v[2][i + 1] : hi[2];
                const float zm2 = (i > 0) ? v[2][i - 1] : lo[2];
                float a = rc;
                a = fmaf(w[0], zp0 - rc, a);
                a = fmaf(w[1], v[0][i] - rc, a);
                a = fmaf(w[2], zm0 - rc, a);
                a = fmaf(w[3], zp1 - rc, a);
                a = fmaf(w[4], zm1 - rc, a);
                a = fmaf(w[5], zp2 - rc, a);
                a = fmaf(w[6], v[2][i] - rc, a);
                a = fmaf(w[7], zm2 - rc, a);
                out4[i] = a;
            }
        }
        const float4 o = make_float4(out4[0], out4[1], out4[2], out4[3]);
        if (STORE) *(float4*)(gq + zb) = o;
        else       *(float4*)(dst + cb + zb) = o;
    }
}

__global__ __launch_bounds__(256) void iter3(const H8* __restrict__ wt,
                                             const float* __restrict__ rin,
                                             float* __restrict__ rout) {
    __shared__ float A[LSZ];
    __shared__ float B[LSZ];
    const int t  = threadIdx.x;
    const int bx = blockIdx.x & 31, by = blockIdx.x >> 5;  // 32 x 16 blocks
    const bool act = t < NCOL;
    const int rx = t / RY, ry = t - rx * RY;
    const int gx = bx * TXB - 2 + rx, gy = by * TYB - 2 + ry;
    const int gxc = iclamp(gx, 0, 255), gyc = iclamp(gy, 0, 255);
    const int cb = t * CSTR + LOFF;

    for (int i = t; i < LSZ; i += 256) { A[i] = 0.f; B[i] = 0.f; }
    __syncthreads();
    if (act) {
        const float* p = rin + ((gxc << 8) + gyc) * 32;
#pragma unroll
        for (int j = 0; j < 8; ++j)
            *(float4*)(A + cb + 4 * j) = *(const float4*)(p + 4 * j);
    }
    __syncthreads();

    const bool in0 = act && rx >= 1 && rx <= RX - 2 && ry >= 1 && ry <= RY - 2;
    const bool in1 = act && rx >= 2 && rx <= RX - 3 && ry >= 1 && ry <= RY - 2;
    const bool in2 = act && rx >= 2 && rx <= RX - 3 && ry >= 2 && ry <= RY - 3;

    fstep<0, false>(wt, A, B, nullptr, cb, gxc, gyc, in0);
    __syncthreads();
    fstep<1, false>(wt, B, A, nullptr, cb, gxc, gyc, in1);
    __syncthreads();
    float* gq = rout + ((gx << 8) + gy) * 32;   // in2 => gx,gy in-volume
    fstep<2, true>(wt, A, nullptr, gq, cb, gxc, gyc, in2);
}

// ---------------- fallback (R1-proven): direct-from-guidance steps ----------------
template <int DIR>
__global__ __launch_bounds__(256) void prop_step(const float* __restrict__ g,
                                                 const float* __restrict__ rin,
                                                 float* __restrict__ rout) {
    constexpr int d1[8] = {1, 1, 1, 0, 0, -1, -1, -1};
    constexpr int d2[8] = {1, 0, -1, 1, -1, 1, 0, -1};
    const int t = blockIdx.x * 256 + threadIdx.x;
    const int f0 = t << 2;
    const int z = f0 & 31, y = (f0 >> 5) & 255, x = f0 >> 13;
    const int gb0 = DIR * 8 * NV;

    float as[4] = {0, 0, 0, 0}, ac[4] = {0, 0, 0, 0};
    float4 rc;

    if (DIR == 0) {
        rc = *(const float4*)(rin + f0);
#pragma unroll
        for (int k = 0; k < 8; ++k) {
            const int a = x + d1[k], b = y + d2[k];
            const bool valid = ((unsigned)a < 256u) & ((unsigned)b < 256u);
            const int ofs = f0 + d1[k] * YZ + d2[k] * 32;
            const float4 rv = *(const float4*)(rin + iclamp(ofs, 0, NV - 4));
            float4 gv = *(const float4*)(g + iclamp(gb0 + k * NV + ofs, 0, GEND - 4));
            if (!valid) { gv.x = 0.f; gv.y = 0.f; gv.z = 0.f; gv.w = 0.f; }
            as[0] += fabsf(gv.x); as[1] += fabsf(gv.y);
            as[2] += fabsf(gv.z); as[3] += fabsf(gv.w);
            ac[0] = fmaf(gv.x, rv.x - rc.x, ac[0]); ac[1] = fmaf(gv.y, rv.y - rc.y, ac[1]);
            ac[2] = fmaf(gv.z, rv.z - rc.z, ac[2]); ac[3] = fmaf(gv.w, rv.w - rc.w, ac[3]);
        }
    } else {
        const int s1 = (DIR == 1) ? YZ : 32;
        const int c1 = (DIR == 1) ? x : y;
        float4 rv[3]; float rl[3], rr[3];
#pragma unroll
        for (int j = 0; j < 3; ++j) {
            const int ro = f0 + (1 - j) * s1;
            rv[j] = *(const float4*)(rin + iclamp(ro, 0, NV - 4));
            rl[j] = rin[iclamp(ro - 1, 0, NV - 1)];
            rr[j] = rin[iclamp(ro + 4, 0, NV - 1)];
        }
        rc = rv[1];
        const bool zlo = (z > 0), zhi = (z < 28);
#pragma unroll
        for (int k = 0; k < 8; ++k) {
            const int j = 1 - d1[k];
            const bool vrow = (unsigned)(c1 + d1[k]) < 256u;
            const int gb = gb0 + k * NV + f0 + d1[k] * s1;
            float4 gv = *(const float4*)(g + iclamp(gb, 0, GEND - 4));
            if (!vrow) { gv.x = 0.f; gv.y = 0.f; gv.z = 0.f; gv.w = 0.f; }
            float4 gk, rk;
            if (d2[k] == 1) {
                float ge = g[iclamp(gb + 4, 0, GEND - 1)];
                ge = (vrow && zhi) ? ge : 0.f;
                gk = make_float4(gv.y, gv.z, gv.w, ge);
                rk = make_float4(rv[j].y, rv[j].z, rv[j].w, rr[j]);
            } else if (d2[k] == -1) {
                float ge = g[iclamp(gb - 1, 0, GEND - 1)];
                ge = (vrow && zlo) ? ge : 0.f;
                gk = make_float4(ge, gv.x, gv.y, gv.z);
                rk = make_float4(rl[j], rv[j].x, rv[j].y, rv[j].z);
            } else {
                gk = gv; rk = rv[j];
            }
            as[0] += fabsf(gk.x); as[1] += fabsf(gk.y);
            as[2] += fabsf(gk.z); as[3] += fabsf(gk.w);
            ac[0] = fmaf(gk.x, rk.x - rc.x, ac[0]); ac[1] = fmaf(gk.y, rk.y - rc.y, ac[1]);
            ac[2] = fmaf(gk.z, rk.z - rc.z, ac[2]); ac[3] = fmaf(gk.w, rk.w - rc.w, ac[3]);
        }
    }

    float4 o;
    o.x = rc.x + ac[0] * __builtin_amdgcn_rcpf(as[0]);
    o.y = rc.y + ac[1] * __builtin_amdgcn_rcpf(as[1]);
    o.z = rc.z + ac[2] * __builtin_amdgcn_rcpf(as[2]);
    o.w = rc.w + ac[3] * __builtin_amdgcn_rcpf(as[3]);
    *(float4*)(rout + f0) = o;
}

extern "C" void kernel_launch(void* const* d_in, const int* in_sizes, int n_in,
                              void* d_out, int out_size, void* d_ws, size_t ws_size,
                              hipStream_t stream) {
    const float* g    = (const float*)d_in[0];
    const float* blur = (const float*)d_in[1];
    float* out = (float*)d_out;

    const size_t WBYTES = (size_t)3 * NV * sizeof(H8);            // 96 MiB
    const size_t NEED   = WBYTES + (size_t)2 * NV * sizeof(float);

    if (ws_size >= NEED) {
        H8*    wt   = (H8*)d_ws;
        float* bufA = (float*)((char*)d_ws + WBYTES);
        float* bufB = bufA + NV;

        make_w<<<dim3(3 * NG / 256), dim3(256), 0, stream>>>(g, wt);
        iter3<<<dim3(512), dim3(256), 0, stream>>>(wt, blur, bufA);
        iter3<<<dim3(512), dim3(256), 0, stream>>>(wt, bufA, bufB);
        iter3<<<dim3(512), dim3(256), 0, stream>>>(wt, bufB, out);
    } else {
        // fallback: R1-proven direct path (needs only 8 MiB of ws)
        float* ws = (float*)d_ws;
        const dim3 block(256), sgrid(NG / 256);
        const float* src = blur;
        for (int step = 0; step < 9; ++step) {
            float* dst = (step & 1) ? ws : out;
            switch (step % 3) {
                case 0: prop_step<0><<<sgrid, block, 0, stream>>>(g, src, dst); break;
                case 1: prop_step<1><<<sgrid, block, 0, stream>>>(g, src, dst); break;
                case 2: prop_step<2><<<sgrid, block, 0, stream>>>(g, src, dst); break;
            }
            src = dst;
        }
    }
}